// Round 13
// baseline (57.859 us; speedup 1.0000x reference)
//
#include <hip/hip_runtime.h>
#include <hip/hip_bf16.h>
#include <math.h>

#define Bn 512
#define Vn 6890
#define NBn 10
#define Pn 207
#define N3n 20670   // Vn*3
#define KP 224      // padded K: 0-206 pf, 207-216 betas, 217 vtpl_hi, 218 vtpl_lo
#define VPAD 6912   // padded vertex rows for W (108*64)

typedef __attribute__((ext_vector_type(8))) _Float16 half8;
typedef __attribute__((ext_vector_type(4))) float f32x4;

__constant__ int c_par[24] = {-1,0,0,0,1,2,3,4,5,6,7,8,9,9,9,12,13,14,16,17,18,19,20,21};
__constant__ int c_lvl[10] = {0,1,4,7,10,15,18,20,22,24};   // chain depth-level ranges

// ================= BIG PATH (fp16 MFMA) =================

// ---- k_prep: jsjt partials (0..191) U B f16 staged-conv (192..839) U W f16 (840..1703) ----
__global__ __launch_bounds__(256) void k_prep(
    const float* __restrict__ Jreg, const float* __restrict__ vtpl,
    const float* __restrict__ sdirs, const float* __restrict__ pdirs,
    const float* __restrict__ W, float* __restrict__ part,
    _Float16* __restrict__ B_h, _Float16* __restrict__ W_h)
{
  const int tid = threadIdx.x;
  __shared__ float wred[4][33];
  __shared__ __align__(16) float tile[224][36];

  if (blockIdx.x < 192) {
    // per-joint jsjt partials: w loaded once for 3 components, sdirs contiguous
    const int j = blockIdx.x % 24;
    const int chunk = blockIdx.x / 24;        // 0..7
    const int lane = tid & 63, wv = tid >> 6;
    const int vlo = chunk * 862;
    const int vhi = min(Vn, vlo + 862);
    float acc[33];
#pragma unroll
    for (int k = 0; k < 33; k++) acc[k] = 0.f;
    for (int v = vlo + tid; v < vhi; v += 256) {
      float w = Jreg[(size_t)j * Vn + v];
      const float* sp = sdirs + (size_t)v * 30;
#pragma unroll
      for (int c = 0; c < 3; c++) {
#pragma unroll
        for (int l = 0; l < 10; l++) acc[c*11 + l] += w * sp[c*10 + l];
        acc[c*11 + 10] += w * vtpl[v*3 + c];
      }
    }
#pragma unroll
    for (int k = 0; k < 33; k++) {
      float s = acc[k];
      for (int off = 32; off > 0; off >>= 1) s += __shfl_xor(s, off);
      if (lane == 0) wred[wv][k] = s;
    }
    __syncthreads();
    if (tid < 33) {
      float s = wred[0][tid] + wred[1][tid] + wred[2][tid] + wred[3][tid];
      int c = tid / 11, k = tid % 11;
      part[(size_t)chunk * 792 + (j*3 + c) * 11 + k] = s;
    }
  } else if (blockIdx.x < 840) {
    // B-conv: block owns 32 columns (128B-aligned) -> pdirs read exactly once, coalesced
    const int p = blockIdx.x - 192;           // 0..647
    const int cols0 = p * 32;
    for (int idx = tid; idx < 207 * 8; idx += 256) {
      int row = idx >> 3, cq = (idx & 7) << 2;
      int gc = cols0 + cq;
      float4 v4 = {0.f, 0.f, 0.f, 0.f};
      if (gc + 3 < N3n) {
        v4 = *(const float4*)(pdirs + (size_t)row * N3n + gc);
      } else if (gc < N3n) {
        float t[4];
#pragma unroll
        for (int e = 0; e < 4; e++) t[e] = (gc + e < N3n) ? pdirs[(size_t)row * N3n + gc + e] : 0.f;
        v4 = make_float4(t[0], t[1], t[2], t[3]);
      }
      *(float4*)&tile[row][cq] = v4;
    }
    for (int idx = tid; idx < 17 * 32; idx += 256) {
      int r = idx >> 5, cc = idx & 31;
      int k = 207 + r;
      int gc = cols0 + cc;
      float f = 0.f;
      if (gc < N3n) {
        if (k < 217)      f = sdirs[(size_t)gc * 10 + (k - 207)];
        else if (k == 217) f = (float)(_Float16)vtpl[gc];
        else if (k == 218) { float tv = vtpl[gc]; f = tv - (float)(_Float16)tv; }
      }
      tile[k][cc] = f;
    }
    __syncthreads();
    for (int idx = tid; idx < 896; idx += 256) {
      int pl = idx >> 6;                      // 0..13
      int l  = idx & 63;
      int ntl = pl / 7, s = pl % 7;
      int colc = ntl * 16 + (l & 15);
      int kb = s * 32 + ((l >> 4) << 3);
      half8 hv;
#pragma unroll
      for (int j = 0; j < 8; j++) hv[j] = (_Float16)tile[kb + j][colc];
      *(half8*)(B_h + ((size_t)(2 * p + ntl) * 7 + s) * 512 + (size_t)l * 8) = hv;
    }
  } else {
    int idx = (blockIdx.x - 840) * 256 + tid;
    if (idx < VPAD * 32) {
      int v = idx >> 5, k = idx & 31;
      float f;
      if (v < Vn && k < 24) f = W[(size_t)v * 24 + k];
      else if (k == 24)     f = 1.0f;     // affine slot pairs with Ar[.,24] = transl
      else                  f = 0.f;
      W_h[idx] = (_Float16)f;
    }
  }
}

// ---- k_pose2: 4 batches/block (1 wave each), shared jsjt reduce ----
__global__ __launch_bounds__(256) void k_pose2(
    const float* __restrict__ betas, const float* __restrict__ body_pose,
    const float* __restrict__ gorient, const float* __restrict__ transl,
    const float* __restrict__ part,
    _Float16* __restrict__ pf_h, _Float16* __restrict__ Ar_h,
    float* __restrict__ out_joints)
{
  const int tid = threadIdx.x;
  const int wave = tid >> 6;
  const int lane = tid & 63;
  const int b = blockIdx.x * 4 + wave;

  __shared__ float JS_s[720];
  __shared__ float Jt_s[72];
  __shared__ float Rs[4][24][9];
  __shared__ float jnt[4][24][3];
  __shared__ float rel[4][24][3];
  __shared__ float A_s[4][24][12];

  for (int idx = tid; idx < 792; idx += 256) {
    float s = 0.f;
#pragma unroll
    for (int y = 0; y < 8; y++) s += part[(size_t)y * 792 + idx];
    int bid = idx / 11, k = idx % 11;
    if (k < 10) JS_s[bid * 10 + k] = s;
    else        Jt_s[bid] = s;
  }

  if (lane < 24) {
    float x, y, z;
    if (lane == 0) { x = gorient[b*3+0]; y = gorient[b*3+1]; z = gorient[b*3+2]; }
    else { int o = b*69 + (lane-1)*3; x = body_pose[o]; y = body_pose[o+1]; z = body_pose[o+2]; }
    float ang = sqrtf(x*x + y*y + z*z) + 1e-8f;
    float inv = 1.0f / ang;
    float ux = x*inv, uy = y*inv, uz = z*inv;
    float s = sinf(ang), cc = cosf(ang), omc = 1.0f - cc;
    float K[9] = {0.f, -uz, uy,  uz, 0.f, -ux,  -uy, ux, 0.f};
#pragma unroll
    for (int mm = 0; mm < 3; mm++)
#pragma unroll
      for (int nn = 0; nn < 3; nn++) {
        float kk = K[mm*3+0]*K[0+nn] + K[mm*3+1]*K[3+nn] + K[mm*3+2]*K[6+nn];
        float eye = (mm == nn) ? 1.0f : 0.0f;
        Rs[wave][lane][mm*3+nn] = eye + s*K[mm*3+nn] + omc*kk;
      }
  }
  __syncthreads();   // JS_s + Rs visible

  for (int idx = lane; idx < 72; idx += 64) {
    float a = Jt_s[idx];
#pragma unroll
    for (int l = 0; l < 10; l++) a += betas[b*10 + l] * JS_s[idx*10 + l];
    jnt[wave][idx/3][idx%3] = a;
  }
  for (int idx = lane; idx < KP; idx += 64) {
    float f = 0.f;
    if (idx < Pn) {
      int j = 1 + idx / 9, e = idx % 9;
      float eye = (e == 0 || e == 4 || e == 8) ? 1.0f : 0.0f;
      f = Rs[wave][j][e] - eye;
    } else if (idx < 217) {
      f = betas[b*10 + (idx - 207)];
    } else if (idx < 219) {
      f = 1.0f;
    }
    pf_h[(size_t)b * KP + idx] = (_Float16)f;
  }
  __syncthreads();
  for (int idx = lane; idx < 72; idx += 64) {
    int j = idx/3, cc = idx%3;
    float r = jnt[wave][j][cc];
    if (j > 0) r -= jnt[wave][c_par[j]][cc];
    rel[wave][j][cc] = r;
  }
  __syncthreads();
  if (lane < 12) {
    int m = lane/4, nn = lane%4;
    A_s[wave][0][lane] = (nn < 3) ? Rs[wave][0][m*3+nn] : rel[wave][0][m];
  }
  __syncthreads();
  for (int lev = 1; lev <= 8; lev++) {
    const int s0 = c_lvl[lev], s1 = c_lvl[lev + 1];
    const int jj = lane / 12, r = lane % 12;
    if (jj < s1 - s0) {
      const int i = s0 + jj;
      const int p = c_par[i];
      const int m = r >> 2, nn = r & 3;
      float v;
      if (nn < 3)
        v = A_s[wave][p][m*4+0]*Rs[wave][i][0+nn] + A_s[wave][p][m*4+1]*Rs[wave][i][3+nn] + A_s[wave][p][m*4+2]*Rs[wave][i][6+nn];
      else
        v = A_s[wave][p][m*4+0]*rel[wave][i][0] + A_s[wave][p][m*4+1]*rel[wave][i][1] + A_s[wave][p][m*4+2]*rel[wave][i][2] + A_s[wave][p][m*4+3];
      A_s[wave][i][r] = v;
    }
    __syncthreads();
  }
  for (int idx = lane; idx < 72; idx += 64) {
    int j = idx/3, cc = idx%3;
    out_joints[(size_t)b * 72 + idx] = A_s[wave][j][cc*4+3] + transl[b*3+cc];
  }
  for (int idx = lane; idx < 512; idx += 64) {
    int e = idx >> 5, k = idx & 31;
    float a = 0.f;
    if (e < 12 && k < 24) {
      int m = e >> 2, nn = e & 3;
      if (nn < 3) a = A_s[wave][k][m*4+nn];
      else a = A_s[wave][k][m*4+3] - (A_s[wave][k][m*4+0]*jnt[wave][k][0] + A_s[wave][k][m*4+1]*jnt[wave][k][1] + A_s[wave][k][m*4+2]*jnt[wave][k][2]);
    } else if (k == 24 && e < 12 && (e & 3) == 3) {
      a = transl[b*3 + (e >> 2)];
    }
    Ar_h[(size_t)b * 512 + idx] = (_Float16)a;
  }
}

// ---- k_mm6: 2 x (32 batches) x 64 vertices per block, prefetched fragments ----
// grid 896: r8 = lin&7 (XCD slot), k3 = lin>>3; bp = k3&7, m8 = k3>>3; v_t = r8*14+m8.
__global__ __launch_bounds__(256) void k_mm6(
    const _Float16* __restrict__ pf_h, const _Float16* __restrict__ B_h,
    const _Float16* __restrict__ W_h, const _Float16* __restrict__ Ar_h,
    float* __restrict__ out)
{
  const int lin = blockIdx.x;
  const int r8 = lin & 7;
  const int k3 = lin >> 3;        // 0..111
  const int bp = k3 & 7;          // b-pair 0..7
  const int m8 = k3 >> 3;         // 0..13
  const int v_t = r8 * 14 + m8;
  if (v_t >= 108) return;

  const int tid = threadIdx.x;
  const int l = tid & 63;
  const int wave = tid >> 6;
  const int v0 = v_t * 64;

  __shared__ __align__(16) float vpT[192 * 32];   // [col=3v+comp][row=batch], XOR-swizzled

  const int c0 = l & 15;
  const int kk0 = (l >> 4) << 3;
  const int ntb = v_t * 12 + wave * 3;
  const int g = l >> 4;           // output component (0..2); 3 = padding
  const int kk = g << 3;

  // W fragments: b-independent -> load ONCE, before everything (full kernel to land)
  half8 wh[4];
#pragma unroll
  for (int mt = 0; mt < 4; mt++)
    wh[mt] = *(const half8*)(W_h + (size_t)(v0 + mt * 16 + c0) * 32 + kk);

#pragma unroll
  for (int half = 0; half < 2; half++) {
    const int b0 = (bp * 2 + half) * 32;

    // Ar prefetch for this b-tile: issues before phase-1 MFMAs, lands during them
    half8 ah[8];
#pragma unroll
    for (int i = 0; i < 8; i++)
      ah[i] = *(const half8*)(Ar_h + (size_t)(b0 + wave * 8 + i) * 512 + c0 * 32 + kk);

    if (half) __syncthreads();   // prior phase-2 vpT reads complete before overwrite

    // ---- phase 1: v_posed GEMM; 2 A-row-tiles share B fragments
    f32x4 acc[2][3];
#pragma unroll
    for (int t = 0; t < 2; t++)
#pragma unroll
      for (int n = 0; n < 3; n++) acc[t][n] = (f32x4){0.f, 0.f, 0.f, 0.f};

#pragma unroll
    for (int s = 0; s < 7; s++) {
      half8 bv[3];
#pragma unroll
      for (int n = 0; n < 3; n++)
        bv[n] = *(const half8*)(B_h + ((size_t)(ntb + n) * 7 + s) * 512 + l * 8);
#pragma unroll
      for (int t = 0; t < 2; t++) {
        half8 fa = *(const half8*)(pf_h + (size_t)(b0 + t * 16 + c0) * KP + kk0 + s * 32);
#pragma unroll
        for (int n = 0; n < 3; n++)
          acc[t][n] = __builtin_amdgcn_mfma_f32_16x16x32_f16(fa, bv[n], acc[t][n], 0, 0, 0);
      }
    }
    {
      const int rowq = (l >> 4) * 4;
#pragma unroll
      for (int t = 0; t < 2; t++)
#pragma unroll
        for (int n = 0; n < 3; n++) {
          const int col = wave * 48 + n * 16 + c0;
          const int rowb = t * 16 + rowq;
          *(f32x4*)&vpT[col * 32 + (rowb ^ ((col & 7) << 2))] = acc[t][n];
        }
    }
    __syncthreads();

    // ---- phase 2 + epilogue (W/Ar already in registers)
#pragma unroll
    for (int mt = 0; mt < 4; mt++) {
      const int vl2 = mt * 16 + c0;
      const int v = v0 + vl2;
      const bool ok = (g < 3) && (v < Vn);
      const int colx = 3 * vl2, coly = colx + 1, colz = colx + 2;
#pragma unroll
      for (int q = 0; q < 2; q++) {
        const int rb = wave * 8 + q * 4;
        f32x4 X = *(const f32x4*)&vpT[colx * 32 + (rb ^ ((colx & 7) << 2))];
        f32x4 Y = *(const f32x4*)&vpT[coly * 32 + (rb ^ ((coly & 7) << 2))];
        f32x4 Z = *(const f32x4*)&vpT[colz * 32 + (rb ^ ((colz & 7) << 2))];
#pragma unroll
        for (int r = 0; r < 4; r++) {
          f32x4 t = {0.f, 0.f, 0.f, 0.f};
          t = __builtin_amdgcn_mfma_f32_16x16x32_f16(ah[q * 4 + r], wh[mt], t, 0, 0, 0);
          if (ok) {
            const int bl = wave * 8 + q * 4 + r;
            out[((size_t)(b0 + bl) * Vn + v) * 3 + g] = t[0]*X[r] + t[1]*Y[r] + t[2]*Z[r] + t[3];
          }
        }
      }
    }
  }
}

// ================= FALLBACK PATH (proven round-4 kernels) =================

__global__ __launch_bounds__(256) void k_jsjt_part(
    const float* __restrict__ Jreg, const float* __restrict__ vtpl,
    const float* __restrict__ sdirs, float* __restrict__ part)
{
  const int bid = blockIdx.x;
  const int chunk = blockIdx.y;
  const int j = bid / 3, c = bid % 3;
  const int tid = threadIdx.x;
  const int vlo = chunk * 862;
  const int vhi = min(Vn, vlo + 862);
  float acc[11];
#pragma unroll
  for (int k = 0; k < 11; k++) acc[k] = 0.f;
  for (int v = vlo + tid; v < vhi; v += 256) {
    float w = Jreg[(size_t)j * Vn + v];
    int n = v * 3 + c;
#pragma unroll
    for (int l = 0; l < 10; l++) acc[l] += w * sdirs[(size_t)n * 10 + l];
    acc[10] += w * vtpl[n];
  }
  __shared__ float red[256];
  for (int k = 0; k < 11; k++) {
    red[tid] = acc[k];
    __syncthreads();
    for (int s = 128; s > 0; s >>= 1) {
      if (tid < s) red[tid] += red[tid + s];
      __syncthreads();
    }
    if (tid == 0) part[(size_t)chunk * 792 + bid * 11 + k] = red[0];
    __syncthreads();
  }
}

__global__ __launch_bounds__(1024) void k_jsjt_red(
    const float* __restrict__ part, float* __restrict__ JS, float* __restrict__ Jt)
{
  const int t = threadIdx.x;
  if (t >= 792) return;
  float s = 0.f;
#pragma unroll
  for (int y = 0; y < 8; y++) s += part[(size_t)y * 792 + t];
  int bid = t / 11, k = t % 11;
  if (k < 10) JS[bid * 10 + k] = s;
  else        Jt[bid] = s;
}

__global__ __launch_bounds__(64) void k_pose_fb(
    const float* __restrict__ betas, const float* __restrict__ body_pose,
    const float* __restrict__ gorient, const float* __restrict__ transl,
    const float* __restrict__ JS, const float* __restrict__ Jt,
    float* __restrict__ pf_ws, float* __restrict__ Ar_ws,
    float* __restrict__ out_joints)
{
  const int b = blockIdx.x;
  const int tid = threadIdx.x;
  __shared__ float Rs[24][9];
  __shared__ float jnt[24][3];
  __shared__ float rel[24][3];
  __shared__ float A_s[24][12];

  if (tid < 24) {
    float x, y, z;
    if (tid == 0) { x = gorient[b*3+0]; y = gorient[b*3+1]; z = gorient[b*3+2]; }
    else { int o = b*69 + (tid-1)*3; x = body_pose[o]; y = body_pose[o+1]; z = body_pose[o+2]; }
    float ang = sqrtf(x*x + y*y + z*z) + 1e-8f;
    float inv = 1.0f / ang;
    float ux = x*inv, uy = y*inv, uz = z*inv;
    float s = sinf(ang), cc = cosf(ang), omc = 1.0f - cc;
    float K[9] = {0.f, -uz, uy,  uz, 0.f, -ux,  -uy, ux, 0.f};
#pragma unroll
    for (int mm = 0; mm < 3; mm++)
#pragma unroll
      for (int nn = 0; nn < 3; nn++) {
        float kk = K[mm*3+0]*K[0+nn] + K[mm*3+1]*K[3+nn] + K[mm*3+2]*K[6+nn];
        float eye = (mm == nn) ? 1.0f : 0.0f;
        Rs[tid][mm*3+nn] = eye + s*K[mm*3+nn] + omc*kk;
      }
  }
  for (int idx = tid; idx < 72; idx += 64) {
    float a = Jt[idx];
#pragma unroll
    for (int l = 0; l < 10; l++) a += betas[b*10 + l] * JS[idx*10 + l];
    jnt[idx/3][idx%3] = a;
  }
  __syncthreads();
  for (int idx = tid; idx < Pn; idx += 64) {
    int j = 1 + idx / 9, e = idx % 9;
    float eye = (e == 0 || e == 4 || e == 8) ? 1.0f : 0.0f;
    pf_ws[(size_t)b * Pn + idx] = Rs[j][e] - eye;
  }
  for (int idx = tid; idx < 72; idx += 64) {
    int j = idx/3, cc = idx%3;
    float r = jnt[j][cc];
    if (j > 0) r -= jnt[c_par[j]][cc];
    rel[j][cc] = r;
  }
  __syncthreads();
  if (tid < 12) {
    int m = tid/4, nn = tid%4;
    A_s[0][tid] = (nn < 3) ? Rs[0][m*3+nn] : rel[0][m];
  }
  __syncthreads();
  for (int i = 1; i < 24; i++) {
    if (tid < 12) {
      int m = tid/4, nn = tid%4;
      int p = c_par[i];
      float v;
      if (nn < 3)
        v = A_s[p][m*4+0]*Rs[i][0+nn] + A_s[p][m*4+1]*Rs[i][3+nn] + A_s[p][m*4+2]*Rs[i][6+nn];
      else
        v = A_s[p][m*4+0]*rel[i][0] + A_s[p][m*4+1]*rel[i][1] + A_s[p][m*4+2]*rel[i][2] + A_s[p][m*4+3];
      A_s[i][tid] = v;
    }
    __syncthreads();
  }
  for (int idx = tid; idx < 72; idx += 64) {
    int j = idx/3, cc = idx%3;
    out_joints[(size_t)b * 72 + idx] = A_s[j][cc*4+3] + transl[b*3+cc];
  }
  for (int idx = tid; idx < 288; idx += 64) {
    int j = idx/12, r = idx%12, m = r/4, nn = r%4;
    float v;
    if (nn < 3) v = A_s[j][m*4+nn];
    else v = A_s[j][m*4+3] - (A_s[j][m*4+0]*jnt[j][0] + A_s[j][m*4+1]*jnt[j][1] + A_s[j][m*4+2]*jnt[j][2]);
    Ar_ws[(size_t)b * 288 + idx] = v;
  }
}

__global__ __launch_bounds__(192) void k_verts_fb(
    const float* __restrict__ betas, const float* __restrict__ transl,
    const float* __restrict__ vtpl, const float* __restrict__ sdirs,
    const float* __restrict__ pdirs, const float* __restrict__ W,
    const float* __restrict__ pf_ws, const float* __restrict__ Ar_ws,
    float* __restrict__ out)
{
  const int tid = threadIdx.x;
  const int b0 = blockIdx.x * 16;
  const int v0 = blockIdx.y * 128;
  const int n0 = v0 * 3;
  __shared__ __align__(16) float pf_s[Pn][16];
  __shared__ __align__(16) float Ar_s[16][288];
  __shared__ __align__(16) float vp_s[16][384];
  __shared__ float betas_s[16][NBn];
  __shared__ float transl_s[16][3];
  for (int idx = tid; idx < Pn * 16; idx += 192) {
    int p = idx >> 4, bi = idx & 15;
    pf_s[p][bi] = pf_ws[(size_t)(b0 + bi) * Pn + p];
  }
  for (int idx = tid; idx < 16 * 288; idx += 192)
    Ar_s[idx / 288][idx % 288] = Ar_ws[(size_t)b0 * 288 + idx];
  for (int idx = tid; idx < 16 * NBn; idx += 192)
    betas_s[idx / NBn][idx % NBn] = betas[(size_t)b0 * NBn + idx];
  for (int idx = tid; idx < 48; idx += 192)
    transl_s[idx / 3][idx % 3] = transl[(size_t)b0 * 3 + idx];
  __syncthreads();
  const int n = n0 + 2 * tid;
  const bool valid = (n < N3n);
  float acc0[16], acc1[16];
#pragma unroll
  for (int i = 0; i < 16; i++) { acc0[i] = 0.f; acc1[i] = 0.f; }
  for (int p = 0; p < Pn; p++) {
    float pd0 = 0.f, pd1 = 0.f;
    if (valid) { float2 t = *(const float2*)(pdirs + (size_t)p * N3n + n); pd0 = t.x; pd1 = t.y; }
    const float4* row = (const float4*)(pf_s[p]);
#pragma unroll
    for (int q = 0; q < 4; q++) {
      float4 f = row[q];
      acc0[4*q+0] += f.x * pd0;  acc1[4*q+0] += f.x * pd1;
      acc0[4*q+1] += f.y * pd0;  acc1[4*q+1] += f.y * pd1;
      acc0[4*q+2] += f.z * pd0;  acc1[4*q+2] += f.z * pd1;
      acc0[4*q+3] += f.w * pd0;  acc1[4*q+3] += f.w * pd1;
    }
  }
  float sd0[10], sd1[10], vt0 = 0.f, vt1 = 0.f;
#pragma unroll
  for (int l = 0; l < 10; l++) { sd0[l] = 0.f; sd1[l] = 0.f; }
  if (valid) {
    for (int l = 0; l < 10; l++) { sd0[l] = sdirs[(size_t)n*10 + l]; sd1[l] = sdirs[(size_t)n*10 + 10 + l]; }
    vt0 = vtpl[n]; vt1 = vtpl[n+1];
  }
#pragma unroll
  for (int bi = 0; bi < 16; bi++) {
    float s0 = vt0, s1 = vt1;
#pragma unroll
    for (int l = 0; l < 10; l++) { float bb = betas_s[bi][l]; s0 += bb*sd0[l]; s1 += bb*sd1[l]; }
    acc0[bi] += s0; acc1[bi] += s1;
  }
#pragma unroll
  for (int bi = 0; bi < 16; bi++) { vp_s[bi][2*tid] = acc0[bi]; vp_s[bi][2*tid+1] = acc1[bi]; }
  __syncthreads();
  const int m = tid / 64;
  const int vl = tid % 64;
  const int va = v0 + vl, vb = v0 + vl + 64;
  const bool va_ok = (va < Vn), vb_ok = (vb < Vn);
  float Wr0[24], Wr1[24];
#pragma unroll
  for (int j = 0; j < 24; j++) { Wr0[j] = 0.f; Wr1[j] = 0.f; }
  if (va_ok) { const float4* wp = (const float4*)(W + (size_t)va*24);
#pragma unroll
    for (int q = 0; q < 6; q++) { float4 f = wp[q]; Wr0[4*q]=f.x; Wr0[4*q+1]=f.y; Wr0[4*q+2]=f.z; Wr0[4*q+3]=f.w; } }
  if (vb_ok) { const float4* wp = (const float4*)(W + (size_t)vb*24);
#pragma unroll
    for (int q = 0; q < 6; q++) { float4 f = wp[q]; Wr1[4*q]=f.x; Wr1[4*q+1]=f.y; Wr1[4*q+2]=f.z; Wr1[4*q+3]=f.w; } }
  for (int bi = 0; bi < 16; bi++) {
    float Ta0=0.f,Ta1=0.f,Ta2=0.f,Ta3=0.f, Tb0=0.f,Tb1=0.f,Tb2=0.f,Tb3=0.f;
    const float4* arb = (const float4*)(Ar_s[bi]);
#pragma unroll
    for (int j = 0; j < 24; j++) {
      float4 a = arb[j*3 + m];
      float wa = Wr0[j], wb = Wr1[j];
      Ta0 += wa*a.x; Ta1 += wa*a.y; Ta2 += wa*a.z; Ta3 += wa*a.w;
      Tb0 += wb*a.x; Tb1 += wb*a.y; Tb2 += wb*a.z; Tb3 += wb*a.w;
    }
    float tr = transl_s[bi][m];
    if (va_ok) {
      float x = vp_s[bi][vl*3+0], y = vp_s[bi][vl*3+1], z = vp_s[bi][vl*3+2];
      out[((size_t)(b0+bi)*Vn + va)*3 + m] = Ta0*x + Ta1*y + Ta2*z + Ta3 + tr;
    }
    if (vb_ok) {
      float x = vp_s[bi][(vl+64)*3+0], y = vp_s[bi][(vl+64)*3+1], z = vp_s[bi][(vl+64)*3+2];
      out[((size_t)(b0+bi)*Vn + vb)*3 + m] = Tb0*x + Tb1*y + Tb2*z + Tb3 + tr;
    }
  }
}

extern "C" void kernel_launch(void* const* d_in, const int* in_sizes, int n_in,
                              void* d_out, int out_size, void* d_ws, size_t ws_size,
                              hipStream_t stream)
{
  const float *betas=nullptr, *bpose=nullptr, *gorient=nullptr, *transl=nullptr,
              *vtpl=nullptr, *sdirs=nullptr, *pdirs=nullptr, *Jreg=nullptr, *W=nullptr;
  int seen1536 = 0, seen165360 = 0;
  for (int i = 0; i < n_in; i++) {
    const float* p = (const float*)d_in[i];
    switch (in_sizes[i]) {
      case 5120:    betas = p; break;
      case 35328:   bpose = p; break;
      case 20670:   vtpl  = p; break;
      case 206700:  sdirs = p; break;
      case 4278690: pdirs = p; break;
      case 1536:    if (seen1536++ == 0) gorient = p; else transl = p; break;
      case 165360:  if (seen165360++ == 0) Jreg = p; else W = p; break;
      default: break;
    }
  }
  float* out = (float*)d_out;

  float* ws   = (float*)d_ws;
  float* part = ws;                                   // 6336 f
  float* JS   = ws + 6336;                            // 720 f   (fallback)
  float* Jt   = ws + 7056;                            // 72 f    (fallback)
  float* pf   = ws + 7128;                            // 105984 f (fallback)
  float* Ar   = ws + 113112;                          // 147456 f (fallback)
  _Float16* pf_h = (_Float16*)(ws + 260568);          // 114688 h
  _Float16* B_h  = (_Float16*)(ws + 317912);          // 4644864 h
  _Float16* W_h  = (_Float16*)(ws + 2640344);         // 221184 h
  _Float16* Ar_h = (_Float16*)(ws + 2861528);         // 262144 h
  const size_t WS_NEED = (size_t)3123672 * 4;         // 12,494,688 bytes (conservative)
  const bool big = (ws_size >= WS_NEED);

  if (big) {
    k_prep<<<1704, 256, 0, stream>>>(Jreg, vtpl, sdirs, pdirs, W, part, B_h, W_h);
    k_pose2<<<128, 256, 0, stream>>>(betas, bpose, gorient, transl, part,
                                     pf_h, Ar_h, out + (size_t)Bn * Vn * 3);
    k_mm6<<<896, 256, 0, stream>>>(pf_h, B_h, W_h, Ar_h, out);
  } else {
    k_jsjt_part<<<dim3(72, 8), 256, 0, stream>>>(Jreg, vtpl, sdirs, part);
    k_jsjt_red<<<1, 1024, 0, stream>>>(part, JS, Jt);
    k_pose_fb<<<Bn, 64, 0, stream>>>(betas, bpose, gorient, transl, JS, Jt, pf, Ar,
                                     out + (size_t)Bn * Vn * 3);
    k_verts_fb<<<dim3(32, 54), 192, 0, stream>>>(betas, transl, vtpl, sdirs,
                                                 pdirs, W, pf, Ar, out);
  }
}

// Round 14
// 53.205 us; speedup vs baseline: 1.0875x; 1.0875x over previous
//
#include <hip/hip_runtime.h>
#include <hip/hip_bf16.h>
#include <math.h>

#define Bn 512
#define Vn 6890
#define NBn 10
#define Pn 207
#define N3n 20670   // Vn*3
#define KP 224      // padded K: 0-206 pf, 207-216 betas, 217 vtpl_hi, 218 vtpl_lo
#define VPAD 6912   // padded vertex rows for W (108*64)

typedef __attribute__((ext_vector_type(8))) _Float16 half8;
typedef __attribute__((ext_vector_type(4))) float f32x4;

__constant__ int c_par[24] = {-1,0,0,0,1,2,3,4,5,6,7,8,9,9,9,12,13,14,16,17,18,19,20,21};
__constant__ int c_lvl[10] = {0,1,4,7,10,15,18,20,22,24};   // chain depth-level ranges

// ================= BIG PATH (fp16 MFMA) =================

// ---- k_prep: jsjt partials (0..191) U B f16 staged-conv (192..839) U W f16 (840..1703) ----
__global__ __launch_bounds__(256) void k_prep(
    const float* __restrict__ Jreg, const float* __restrict__ vtpl,
    const float* __restrict__ sdirs, const float* __restrict__ pdirs,
    const float* __restrict__ W, float* __restrict__ part,
    _Float16* __restrict__ B_h, _Float16* __restrict__ W_h)
{
  const int tid = threadIdx.x;
  __shared__ float wred[4][33];
  __shared__ __align__(16) float tile[224][36];

  if (blockIdx.x < 192) {
    // per-joint jsjt partials: w loaded once for 3 components, sdirs contiguous
    const int j = blockIdx.x % 24;
    const int chunk = blockIdx.x / 24;        // 0..7
    const int lane = tid & 63, wv = tid >> 6;
    const int vlo = chunk * 862;
    const int vhi = min(Vn, vlo + 862);
    float acc[33];
#pragma unroll
    for (int k = 0; k < 33; k++) acc[k] = 0.f;
    for (int v = vlo + tid; v < vhi; v += 256) {
      float w = Jreg[(size_t)j * Vn + v];
      const float* sp = sdirs + (size_t)v * 30;
#pragma unroll
      for (int c = 0; c < 3; c++) {
#pragma unroll
        for (int l = 0; l < 10; l++) acc[c*11 + l] += w * sp[c*10 + l];
        acc[c*11 + 10] += w * vtpl[v*3 + c];
      }
    }
#pragma unroll
    for (int k = 0; k < 33; k++) {
      float s = acc[k];
      for (int off = 32; off > 0; off >>= 1) s += __shfl_xor(s, off);
      if (lane == 0) wred[wv][k] = s;
    }
    __syncthreads();
    if (tid < 33) {
      float s = wred[0][tid] + wred[1][tid] + wred[2][tid] + wred[3][tid];
      int c = tid / 11, k = tid % 11;
      part[(size_t)chunk * 792 + (j*3 + c) * 11 + k] = s;
    }
  } else if (blockIdx.x < 840) {
    // B-conv: block owns 32 columns (128B-aligned) -> pdirs read exactly once, coalesced
    const int p = blockIdx.x - 192;           // 0..647
    const int cols0 = p * 32;
    for (int idx = tid; idx < 207 * 8; idx += 256) {
      int row = idx >> 3, cq = (idx & 7) << 2;
      int gc = cols0 + cq;
      float4 v4 = {0.f, 0.f, 0.f, 0.f};
      if (gc + 3 < N3n) {
        v4 = *(const float4*)(pdirs + (size_t)row * N3n + gc);
      } else if (gc < N3n) {
        float t[4];
#pragma unroll
        for (int e = 0; e < 4; e++) t[e] = (gc + e < N3n) ? pdirs[(size_t)row * N3n + gc + e] : 0.f;
        v4 = make_float4(t[0], t[1], t[2], t[3]);
      }
      *(float4*)&tile[row][cq] = v4;
    }
    for (int idx = tid; idx < 17 * 32; idx += 256) {
      int r = idx >> 5, cc = idx & 31;
      int k = 207 + r;
      int gc = cols0 + cc;
      float f = 0.f;
      if (gc < N3n) {
        if (k < 217)      f = sdirs[(size_t)gc * 10 + (k - 207)];
        else if (k == 217) f = (float)(_Float16)vtpl[gc];
        else if (k == 218) { float tv = vtpl[gc]; f = tv - (float)(_Float16)tv; }
      }
      tile[k][cc] = f;
    }
    __syncthreads();
    for (int idx = tid; idx < 896; idx += 256) {
      int pl = idx >> 6;                      // 0..13
      int l  = idx & 63;
      int ntl = pl / 7, s = pl % 7;
      int colc = ntl * 16 + (l & 15);
      int kb = s * 32 + ((l >> 4) << 3);
      half8 hv;
#pragma unroll
      for (int j = 0; j < 8; j++) hv[j] = (_Float16)tile[kb + j][colc];
      *(half8*)(B_h + ((size_t)(2 * p + ntl) * 7 + s) * 512 + (size_t)l * 8) = hv;
    }
  } else {
    int idx = (blockIdx.x - 840) * 256 + tid;
    if (idx < VPAD * 32) {
      int v = idx >> 5, k = idx & 31;
      float f;
      if (v < Vn && k < 24) f = W[(size_t)v * 24 + k];
      else if (k == 24)     f = 1.0f;     // affine slot pairs with Ar[.,24] = transl
      else                  f = 0.f;
      W_h[idx] = (_Float16)f;
    }
  }
}

// ---- k_pose2: 4 batches/block (1 wave each), shared jsjt reduce ----
__global__ __launch_bounds__(256) void k_pose2(
    const float* __restrict__ betas, const float* __restrict__ body_pose,
    const float* __restrict__ gorient, const float* __restrict__ transl,
    const float* __restrict__ part,
    _Float16* __restrict__ pf_h, _Float16* __restrict__ Ar_h,
    float* __restrict__ out_joints)
{
  const int tid = threadIdx.x;
  const int wave = tid >> 6;
  const int lane = tid & 63;
  const int b = blockIdx.x * 4 + wave;

  __shared__ float JS_s[720];
  __shared__ float Jt_s[72];
  __shared__ float Rs[4][24][9];
  __shared__ float jnt[4][24][3];
  __shared__ float rel[4][24][3];
  __shared__ float A_s[4][24][12];

  for (int idx = tid; idx < 792; idx += 256) {
    float s = 0.f;
#pragma unroll
    for (int y = 0; y < 8; y++) s += part[(size_t)y * 792 + idx];
    int bid = idx / 11, k = idx % 11;
    if (k < 10) JS_s[bid * 10 + k] = s;
    else        Jt_s[bid] = s;
  }

  if (lane < 24) {
    float x, y, z;
    if (lane == 0) { x = gorient[b*3+0]; y = gorient[b*3+1]; z = gorient[b*3+2]; }
    else { int o = b*69 + (lane-1)*3; x = body_pose[o]; y = body_pose[o+1]; z = body_pose[o+2]; }
    float ang = sqrtf(x*x + y*y + z*z) + 1e-8f;
    float inv = 1.0f / ang;
    float ux = x*inv, uy = y*inv, uz = z*inv;
    float s = sinf(ang), cc = cosf(ang), omc = 1.0f - cc;
    float K[9] = {0.f, -uz, uy,  uz, 0.f, -ux,  -uy, ux, 0.f};
#pragma unroll
    for (int mm = 0; mm < 3; mm++)
#pragma unroll
      for (int nn = 0; nn < 3; nn++) {
        float kk = K[mm*3+0]*K[0+nn] + K[mm*3+1]*K[3+nn] + K[mm*3+2]*K[6+nn];
        float eye = (mm == nn) ? 1.0f : 0.0f;
        Rs[wave][lane][mm*3+nn] = eye + s*K[mm*3+nn] + omc*kk;
      }
  }
  __syncthreads();   // JS_s + Rs visible

  for (int idx = lane; idx < 72; idx += 64) {
    float a = Jt_s[idx];
#pragma unroll
    for (int l = 0; l < 10; l++) a += betas[b*10 + l] * JS_s[idx*10 + l];
    jnt[wave][idx/3][idx%3] = a;
  }
  for (int idx = lane; idx < KP; idx += 64) {
    float f = 0.f;
    if (idx < Pn) {
      int j = 1 + idx / 9, e = idx % 9;
      float eye = (e == 0 || e == 4 || e == 8) ? 1.0f : 0.0f;
      f = Rs[wave][j][e] - eye;
    } else if (idx < 217) {
      f = betas[b*10 + (idx - 207)];
    } else if (idx < 219) {
      f = 1.0f;
    }
    pf_h[(size_t)b * KP + idx] = (_Float16)f;
  }
  __syncthreads();
  for (int idx = lane; idx < 72; idx += 64) {
    int j = idx/3, cc = idx%3;
    float r = jnt[wave][j][cc];
    if (j > 0) r -= jnt[wave][c_par[j]][cc];
    rel[wave][j][cc] = r;
  }
  __syncthreads();
  if (lane < 12) {
    int m = lane/4, nn = lane%4;
    A_s[wave][0][lane] = (nn < 3) ? Rs[wave][0][m*3+nn] : rel[wave][0][m];
  }
  __syncthreads();
  for (int lev = 1; lev <= 8; lev++) {
    const int s0 = c_lvl[lev], s1 = c_lvl[lev + 1];
    const int jj = lane / 12, r = lane % 12;
    if (jj < s1 - s0) {
      const int i = s0 + jj;
      const int p = c_par[i];
      const int m = r >> 2, nn = r & 3;
      float v;
      if (nn < 3)
        v = A_s[wave][p][m*4+0]*Rs[wave][i][0+nn] + A_s[wave][p][m*4+1]*Rs[wave][i][3+nn] + A_s[wave][p][m*4+2]*Rs[wave][i][6+nn];
      else
        v = A_s[wave][p][m*4+0]*rel[wave][i][0] + A_s[wave][p][m*4+1]*rel[wave][i][1] + A_s[wave][p][m*4+2]*rel[wave][i][2] + A_s[wave][p][m*4+3];
      A_s[wave][i][r] = v;
    }
    __syncthreads();
  }
  for (int idx = lane; idx < 72; idx += 64) {
    int j = idx/3, cc = idx%3;
    out_joints[(size_t)b * 72 + idx] = A_s[wave][j][cc*4+3] + transl[b*3+cc];
  }
  for (int idx = lane; idx < 512; idx += 64) {
    int e = idx >> 5, k = idx & 31;
    float a = 0.f;
    if (e < 12 && k < 24) {
      int m = e >> 2, nn = e & 3;
      if (nn < 3) a = A_s[wave][k][m*4+nn];
      else a = A_s[wave][k][m*4+3] - (A_s[wave][k][m*4+0]*jnt[wave][k][0] + A_s[wave][k][m*4+1]*jnt[wave][k][1] + A_s[wave][k][m*4+2]*jnt[wave][k][2]);
    } else if (k == 24 && e < 12 && (e & 3) == 3) {
      a = transl[b*3 + (e >> 2)];
    }
    Ar_h[(size_t)b * 512 + idx] = (_Float16)a;
  }
}

// ---- k_mm5: 32 batches x 64 vertices, fp16 MFMA, fp32 vpT (XOR-swizzled, b128 LDS ops) ----
// grid 1792: r8 = lin&7 (XCD slot), k2 = lin>>3; b_t = k2&15, m8 = k2>>4; v_t = r8*14+m8.
__global__ __launch_bounds__(256) void k_mm5(
    const _Float16* __restrict__ pf_h, const _Float16* __restrict__ B_h,
    const _Float16* __restrict__ W_h, const _Float16* __restrict__ Ar_h,
    float* __restrict__ out)
{
  const int lin = blockIdx.x;
  const int r8 = lin & 7;
  const int k2 = lin >> 3;
  const int b_t = k2 & 15;
  const int m8 = k2 >> 4;
  const int v_t = r8 * 14 + m8;
  if (v_t >= 108) return;

  const int tid = threadIdx.x;
  const int l = tid & 63;
  const int wave = tid >> 6;
  const int b0 = b_t * 32;
  const int v0 = v_t * 64;

  __shared__ __align__(16) float vpT[192 * 32];   // [col=3v+comp][row=batch], XOR-swizzled

  // ---- phase 1: v_posed GEMM; 2 A-row-tiles share B fragments
  const int c0 = l & 15;
  const int kk0 = (l >> 4) << 3;
  const int ntb = v_t * 12 + wave * 3;
  f32x4 acc[2][3];
#pragma unroll
  for (int t = 0; t < 2; t++)
#pragma unroll
    for (int n = 0; n < 3; n++) acc[t][n] = (f32x4){0.f, 0.f, 0.f, 0.f};

#pragma unroll
  for (int s = 0; s < 7; s++) {
    half8 bv[3];
#pragma unroll
    for (int n = 0; n < 3; n++)
      bv[n] = *(const half8*)(B_h + ((size_t)(ntb + n) * 7 + s) * 512 + l * 8);
#pragma unroll
    for (int t = 0; t < 2; t++) {
      half8 fa = *(const half8*)(pf_h + (size_t)(b0 + t * 16 + c0) * KP + kk0 + s * 32);
#pragma unroll
      for (int n = 0; n < 3; n++)
        acc[t][n] = __builtin_amdgcn_mfma_f32_16x16x32_f16(fa, bv[n], acc[t][n], 0, 0, 0);
    }
  }
  {
    const int rowq = (l >> 4) * 4;
#pragma unroll
    for (int t = 0; t < 2; t++)
#pragma unroll
      for (int n = 0; n < 3; n++) {
        const int col = wave * 48 + n * 16 + c0;
        const int rowb = t * 16 + rowq;
        *(f32x4*)&vpT[col * 32 + (rowb ^ ((col & 7) << 2))] = acc[t][n];
      }
  }
  __syncthreads();

  // ---- phase 2 + epilogue
  const int c = c0;             // vertex-within-16 / e-row in Ar frag
  const int g = l >> 4;         // output component (0..2); 3 = padding lanes
  const int kk = g << 3;

  half8 wh[4], ah[8];
#pragma unroll
  for (int mt = 0; mt < 4; mt++)
    wh[mt] = *(const half8*)(W_h + (size_t)(v0 + mt * 16 + c) * 32 + kk);
#pragma unroll
  for (int i = 0; i < 8; i++)
    ah[i] = *(const half8*)(Ar_h + (size_t)(b0 + wave * 8 + i) * 512 + c * 32 + kk);

#pragma unroll
  for (int mt = 0; mt < 4; mt++) {
    const int vl2 = mt * 16 + c;
    const int v = v0 + vl2;
    const bool ok = (g < 3) && (v < Vn);
    const int colx = 3 * vl2, coly = colx + 1, colz = colx + 2;
#pragma unroll
    for (int q = 0; q < 2; q++) {
      const int rb = wave * 8 + q * 4;
      f32x4 X = *(const f32x4*)&vpT[colx * 32 + (rb ^ ((colx & 7) << 2))];
      f32x4 Y = *(const f32x4*)&vpT[coly * 32 + (rb ^ ((coly & 7) << 2))];
      f32x4 Z = *(const f32x4*)&vpT[colz * 32 + (rb ^ ((colz & 7) << 2))];
#pragma unroll
      for (int r = 0; r < 4; r++) {
        f32x4 t = {0.f, 0.f, 0.f, 0.f};
        t = __builtin_amdgcn_mfma_f32_16x16x32_f16(ah[q * 4 + r], wh[mt], t, 0, 0, 0);
        if (ok) {
          const int bl = wave * 8 + q * 4 + r;
          out[((size_t)(b0 + bl) * Vn + v) * 3 + g] = t[0]*X[r] + t[1]*Y[r] + t[2]*Z[r] + t[3];
        }
      }
    }
  }
}

// ================= FALLBACK PATH (proven round-4 kernels) =================

__global__ __launch_bounds__(256) void k_jsjt_part(
    const float* __restrict__ Jreg, const float* __restrict__ vtpl,
    const float* __restrict__ sdirs, float* __restrict__ part)
{
  const int bid = blockIdx.x;
  const int chunk = blockIdx.y;
  const int j = bid / 3, c = bid % 3;
  const int tid = threadIdx.x;
  const int vlo = chunk * 862;
  const int vhi = min(Vn, vlo + 862);
  float acc[11];
#pragma unroll
  for (int k = 0; k < 11; k++) acc[k] = 0.f;
  for (int v = vlo + tid; v < vhi; v += 256) {
    float w = Jreg[(size_t)j * Vn + v];
    int n = v * 3 + c;
#pragma unroll
    for (int l = 0; l < 10; l++) acc[l] += w * sdirs[(size_t)n * 10 + l];
    acc[10] += w * vtpl[n];
  }
  __shared__ float red[256];
  for (int k = 0; k < 11; k++) {
    red[tid] = acc[k];
    __syncthreads();
    for (int s = 128; s > 0; s >>= 1) {
      if (tid < s) red[tid] += red[tid + s];
      __syncthreads();
    }
    if (tid == 0) part[(size_t)chunk * 792 + bid * 11 + k] = red[0];
    __syncthreads();
  }
}

__global__ __launch_bounds__(1024) void k_jsjt_red(
    const float* __restrict__ part, float* __restrict__ JS, float* __restrict__ Jt)
{
  const int t = threadIdx.x;
  if (t >= 792) return;
  float s = 0.f;
#pragma unroll
  for (int y = 0; y < 8; y++) s += part[(size_t)y * 792 + t];
  int bid = t / 11, k = t % 11;
  if (k < 10) JS[bid * 10 + k] = s;
  else        Jt[bid] = s;
}

__global__ __launch_bounds__(64) void k_pose_fb(
    const float* __restrict__ betas, const float* __restrict__ body_pose,
    const float* __restrict__ gorient, const float* __restrict__ transl,
    const float* __restrict__ JS, const float* __restrict__ Jt,
    float* __restrict__ pf_ws, float* __restrict__ Ar_ws,
    float* __restrict__ out_joints)
{
  const int b = blockIdx.x;
  const int tid = threadIdx.x;
  __shared__ float Rs[24][9];
  __shared__ float jnt[24][3];
  __shared__ float rel[24][3];
  __shared__ float A_s[24][12];

  if (tid < 24) {
    float x, y, z;
    if (tid == 0) { x = gorient[b*3+0]; y = gorient[b*3+1]; z = gorient[b*3+2]; }
    else { int o = b*69 + (tid-1)*3; x = body_pose[o]; y = body_pose[o+1]; z = body_pose[o+2]; }
    float ang = sqrtf(x*x + y*y + z*z) + 1e-8f;
    float inv = 1.0f / ang;
    float ux = x*inv, uy = y*inv, uz = z*inv;
    float s = sinf(ang), cc = cosf(ang), omc = 1.0f - cc;
    float K[9] = {0.f, -uz, uy,  uz, 0.f, -ux,  -uy, ux, 0.f};
#pragma unroll
    for (int mm = 0; mm < 3; mm++)
#pragma unroll
      for (int nn = 0; nn < 3; nn++) {
        float kk = K[mm*3+0]*K[0+nn] + K[mm*3+1]*K[3+nn] + K[mm*3+2]*K[6+nn];
        float eye = (mm == nn) ? 1.0f : 0.0f;
        Rs[tid][mm*3+nn] = eye + s*K[mm*3+nn] + omc*kk;
      }
  }
  for (int idx = tid; idx < 72; idx += 64) {
    float a = Jt[idx];
#pragma unroll
    for (int l = 0; l < 10; l++) a += betas[b*10 + l] * JS[idx*10 + l];
    jnt[idx/3][idx%3] = a;
  }
  __syncthreads();
  for (int idx = tid; idx < Pn; idx += 64) {
    int j = 1 + idx / 9, e = idx % 9;
    float eye = (e == 0 || e == 4 || e == 8) ? 1.0f : 0.0f;
    pf_ws[(size_t)b * Pn + idx] = Rs[j][e] - eye;
  }
  for (int idx = tid; idx < 72; idx += 64) {
    int j = idx/3, cc = idx%3;
    float r = jnt[j][cc];
    if (j > 0) r -= jnt[c_par[j]][cc];
    rel[j][cc] = r;
  }
  __syncthreads();
  if (tid < 12) {
    int m = tid/4, nn = tid%4;
    A_s[0][tid] = (nn < 3) ? Rs[0][m*3+nn] : rel[0][m];
  }
  __syncthreads();
  for (int i = 1; i < 24; i++) {
    if (tid < 12) {
      int m = tid/4, nn = tid%4;
      int p = c_par[i];
      float v;
      if (nn < 3)
        v = A_s[p][m*4+0]*Rs[i][0+nn] + A_s[p][m*4+1]*Rs[i][3+nn] + A_s[p][m*4+2]*Rs[i][6+nn];
      else
        v = A_s[p][m*4+0]*rel[i][0] + A_s[p][m*4+1]*rel[i][1] + A_s[p][m*4+2]*rel[i][2] + A_s[p][m*4+3];
      A_s[i][tid] = v;
    }
    __syncthreads();
  }
  for (int idx = tid; idx < 72; idx += 64) {
    int j = idx/3, cc = idx%3;
    out_joints[(size_t)b * 72 + idx] = A_s[j][cc*4+3] + transl[b*3+cc];
  }
  for (int idx = tid; idx < 288; idx += 64) {
    int j = idx/12, r = idx%12, m = r/4, nn = r%4;
    float v;
    if (nn < 3) v = A_s[j][m*4+nn];
    else v = A_s[j][m*4+3] - (A_s[j][m*4+0]*jnt[j][0] + A_s[j][m*4+1]*jnt[j][1] + A_s[j][m*4+2]*jnt[j][2]);
    Ar_ws[(size_t)b * 288 + idx] = v;
  }
}

__global__ __launch_bounds__(192) void k_verts_fb(
    const float* __restrict__ betas, const float* __restrict__ transl,
    const float* __restrict__ vtpl, const float* __restrict__ sdirs,
    const float* __restrict__ pdirs, const float* __restrict__ W,
    const float* __restrict__ pf_ws, const float* __restrict__ Ar_ws,
    float* __restrict__ out)
{
  const int tid = threadIdx.x;
  const int b0 = blockIdx.x * 16;
  const int v0 = blockIdx.y * 128;
  const int n0 = v0 * 3;
  __shared__ __align__(16) float pf_s[Pn][16];
  __shared__ __align__(16) float Ar_s[16][288];
  __shared__ __align__(16) float vp_s[16][384];
  __shared__ float betas_s[16][NBn];
  __shared__ float transl_s[16][3];
  for (int idx = tid; idx < Pn * 16; idx += 192) {
    int p = idx >> 4, bi = idx & 15;
    pf_s[p][bi] = pf_ws[(size_t)(b0 + bi) * Pn + p];
  }
  for (int idx = tid; idx < 16 * 288; idx += 192)
    Ar_s[idx / 288][idx % 288] = Ar_ws[(size_t)b0 * 288 + idx];
  for (int idx = tid; idx < 16 * NBn; idx += 192)
    betas_s[idx / NBn][idx % NBn] = betas[(size_t)b0 * NBn + idx];
  for (int idx = tid; idx < 48; idx += 192)
    transl_s[idx / 3][idx % 3] = transl[(size_t)b0 * 3 + idx];
  __syncthreads();
  const int n = n0 + 2 * tid;
  const bool valid = (n < N3n);
  float acc0[16], acc1[16];
#pragma unroll
  for (int i = 0; i < 16; i++) { acc0[i] = 0.f; acc1[i] = 0.f; }
  for (int p = 0; p < Pn; p++) {
    float pd0 = 0.f, pd1 = 0.f;
    if (valid) { float2 t = *(const float2*)(pdirs + (size_t)p * N3n + n); pd0 = t.x; pd1 = t.y; }
    const float4* row = (const float4*)(pf_s[p]);
#pragma unroll
    for (int q = 0; q < 4; q++) {
      float4 f = row[q];
      acc0[4*q+0] += f.x * pd0;  acc1[4*q+0] += f.x * pd1;
      acc0[4*q+1] += f.y * pd0;  acc1[4*q+1] += f.y * pd1;
      acc0[4*q+2] += f.z * pd0;  acc1[4*q+2] += f.z * pd1;
      acc0[4*q+3] += f.w * pd0;  acc1[4*q+3] += f.w * pd1;
    }
  }
  float sd0[10], sd1[10], vt0 = 0.f, vt1 = 0.f;
#pragma unroll
  for (int l = 0; l < 10; l++) { sd0[l] = 0.f; sd1[l] = 0.f; }
  if (valid) {
    for (int l = 0; l < 10; l++) { sd0[l] = sdirs[(size_t)n*10 + l]; sd1[l] = sdirs[(size_t)n*10 + 10 + l]; }
    vt0 = vtpl[n]; vt1 = vtpl[n+1];
  }
#pragma unroll
  for (int bi = 0; bi < 16; bi++) {
    float s0 = vt0, s1 = vt1;
#pragma unroll
    for (int l = 0; l < 10; l++) { float bb = betas_s[bi][l]; s0 += bb*sd0[l]; s1 += bb*sd1[l]; }
    acc0[bi] += s0; acc1[bi] += s1;
  }
#pragma unroll
  for (int bi = 0; bi < 16; bi++) { vp_s[bi][2*tid] = acc0[bi]; vp_s[bi][2*tid+1] = acc1[bi]; }
  __syncthreads();
  const int m = tid / 64;
  const int vl = tid % 64;
  const int va = v0 + vl, vb = v0 + vl + 64;
  const bool va_ok = (va < Vn), vb_ok = (vb < Vn);
  float Wr0[24], Wr1[24];
#pragma unroll
  for (int j = 0; j < 24; j++) { Wr0[j] = 0.f; Wr1[j] = 0.f; }
  if (va_ok) { const float4* wp = (const float4*)(W + (size_t)va*24);
#pragma unroll
    for (int q = 0; q < 6; q++) { float4 f = wp[q]; Wr0[4*q]=f.x; Wr0[4*q+1]=f.y; Wr0[4*q+2]=f.z; Wr0[4*q+3]=f.w; } }
  if (vb_ok) { const float4* wp = (const float4*)(W + (size_t)vb*24);
#pragma unroll
    for (int q = 0; q < 6; q++) { float4 f = wp[q]; Wr1[4*q]=f.x; Wr1[4*q+1]=f.y; Wr1[4*q+2]=f.z; Wr1[4*q+3]=f.w; } }
  for (int bi = 0; bi < 16; bi++) {
    float Ta0=0.f,Ta1=0.f,Ta2=0.f,Ta3=0.f, Tb0=0.f,Tb1=0.f,Tb2=0.f,Tb3=0.f;
    const float4* arb = (const float4*)(Ar_s[bi]);
#pragma unroll
    for (int j = 0; j < 24; j++) {
      float4 a = arb[j*3 + m];
      float wa = Wr0[j], wb = Wr1[j];
      Ta0 += wa*a.x; Ta1 += wa*a.y; Ta2 += wa*a.z; Ta3 += wa*a.w;
      Tb0 += wb*a.x; Tb1 += wb*a.y; Tb2 += wb*a.z; Tb3 += wb*a.w;
    }
    float tr = transl_s[bi][m];
    if (va_ok) {
      float x = vp_s[bi][vl*3+0], y = vp_s[bi][vl*3+1], z = vp_s[bi][vl*3+2];
      out[((size_t)(b0+bi)*Vn + va)*3 + m] = Ta0*x + Ta1*y + Ta2*z + Ta3 + tr;
    }
    if (vb_ok) {
      float x = vp_s[bi][(vl+64)*3+0], y = vp_s[bi][(vl+64)*3+1], z = vp_s[bi][(vl+64)*3+2];
      out[((size_t)(b0+bi)*Vn + vb)*3 + m] = Tb0*x + Tb1*y + Tb2*z + Tb3 + tr;
    }
  }
}

extern "C" void kernel_launch(void* const* d_in, const int* in_sizes, int n_in,
                              void* d_out, int out_size, void* d_ws, size_t ws_size,
                              hipStream_t stream)
{
  const float *betas=nullptr, *bpose=nullptr, *gorient=nullptr, *transl=nullptr,
              *vtpl=nullptr, *sdirs=nullptr, *pdirs=nullptr, *Jreg=nullptr, *W=nullptr;
  int seen1536 = 0, seen165360 = 0;
  for (int i = 0; i < n_in; i++) {
    const float* p = (const float*)d_in[i];
    switch (in_sizes[i]) {
      case 5120:    betas = p; break;
      case 35328:   bpose = p; break;
      case 20670:   vtpl  = p; break;
      case 206700:  sdirs = p; break;
      case 4278690: pdirs = p; break;
      case 1536:    if (seen1536++ == 0) gorient = p; else transl = p; break;
      case 165360:  if (seen165360++ == 0) Jreg = p; else W = p; break;
      default: break;
    }
  }
  float* out = (float*)d_out;

  float* ws   = (float*)d_ws;
  float* part = ws;                                   // 6336 f
  float* JS   = ws + 6336;                            // 720 f   (fallback)
  float* Jt   = ws + 7056;                            // 72 f    (fallback)
  float* pf   = ws + 7128;                            // 105984 f (fallback)
  float* Ar   = ws + 113112;                          // 147456 f (fallback)
  _Float16* pf_h = (_Float16*)(ws + 260568);          // 114688 h
  _Float16* B_h  = (_Float16*)(ws + 317912);          // 4644864 h
  _Float16* W_h  = (_Float16*)(ws + 2640344);         // 221184 h
  _Float16* Ar_h = (_Float16*)(ws + 2861528);         // 262144 h
  const size_t WS_NEED = (size_t)3123672 * 4;         // 12,494,688 bytes (conservative)
  const bool big = (ws_size >= WS_NEED);

  if (big) {
    k_prep<<<1704, 256, 0, stream>>>(Jreg, vtpl, sdirs, pdirs, W, part, B_h, W_h);
    k_pose2<<<128, 256, 0, stream>>>(betas, bpose, gorient, transl, part,
                                     pf_h, Ar_h, out + (size_t)Bn * Vn * 3);
    k_mm5<<<1792, 256, 0, stream>>>(pf_h, B_h, W_h, Ar_h, out);
  } else {
    k_jsjt_part<<<dim3(72, 8), 256, 0, stream>>>(Jreg, vtpl, sdirs, part);
    k_jsjt_red<<<1, 1024, 0, stream>>>(part, JS, Jt);
    k_pose_fb<<<Bn, 64, 0, stream>>>(betas, bpose, gorient, transl, JS, Jt, pf, Ar,
                                     out + (size_t)Bn * Vn * 3);
    k_verts_fb<<<dim3(32, 54), 192, 0, stream>>>(betas, transl, vtpl, sdirs,
                                                 pdirs, W, pf, Ar, out);
  }
}